// Round 5
// baseline (362.097 us; speedup 1.0000x reference)
//
#include <hip/hip_runtime.h>
#include <math.h>
#include <stdint.h>

#define BB    4
#define QQ    200
#define NGT   32
#define DD    65536   // 256*256
#define TOPK  4
#define EPSF  1e-6f
#define QP    208     // padded Q stride

#define QT16  13      // ceil(200/16) q-tiles of 16
#define KG    16      // K-split: wg covers DD/KG = 4096 k
#define KSPAN (DD / KG)       // 4096
#define KQ    (KSPAN / 4)     // 1024 k per wave (contiguous quarter)
#define NIT   (KQ / 32)       // 32 iterations of 32 k

typedef float  f32x4  __attribute__((ext_vector_type(4)));
typedef __bf16 bf16x8 __attribute__((ext_vector_type(8)));

// ---------------------------------------------------------------------------
// K1: bit-pack gt_masks -> packed[b][d] (bit n = gt[b,n,d]); fused zero-init
// of inter+psum (ws is poisoned before every timed call).
__global__ __launch_bounds__(256) void k_pack(const float* __restrict__ gt,
                                              uint32_t* __restrict__ packed,
                                              float* __restrict__ zero_base) {
    int zidx = blockIdx.x * 256 + threadIdx.x;
    if (zidx < BB * NGT * QP + BB * QP) zero_base[zidx] = 0.0f;

    int blk = blockIdx.x;
    int b = blk >> 6;
    int d0 = ((blk & 63) * 256 + threadIdx.x) * 4;
    uint32_t px = 0, py = 0, pz = 0, pw = 0;
    const float* gb = gt + (size_t)b * NGT * DD + d0;
#pragma unroll
    for (int n = 0; n < NGT; ++n) {
        float4 g = *(const float4*)(gb + (size_t)n * DD);
        px |= (g.x > 0.5f ? 1u : 0u) << n;
        py |= (g.y > 0.5f ? 1u : 0u) << n;
        pz |= (g.z > 0.5f ? 1u : 0u) << n;
        pw |= (g.w > 0.5f ? 1u : 0u) << n;
    }
    *(uint4*)(packed + (size_t)b * DD + d0) = make_uint4(px, py, pz, pw);
}

// ---------------------------------------------------------------------------
// K2: tsum[b][n] via popcount-style reduction of packed bits (L2-resident).
__global__ __launch_bounds__(256) void k_tsum(const uint32_t* __restrict__ packed,
                                              float* __restrict__ tsum) {
    int b = blockIdx.x >> 5;
    int n = blockIdx.x & 31;
    const uint4* pp = (const uint4*)(packed + (size_t)b * DD);
    int cnt = 0;
    for (int i = threadIdx.x; i < DD / 4; i += 256) {
        uint4 w = pp[i];
        cnt += (int)((w.x >> n) & 1u) + (int)((w.y >> n) & 1u) +
               (int)((w.z >> n) & 1u) + (int)((w.w >> n) & 1u);
    }
#pragma unroll
    for (int off = 32; off; off >>= 1) cnt += __shfl_xor(cnt, off);
    __shared__ int red[4];
    if ((threadIdx.x & 63) == 0) red[threadIdx.x >> 6] = cnt;
    __syncthreads();
    if (threadIdx.x == 0)
        tsum[blockIdx.x] = (float)(red[0] + red[1] + red[2] + red[3]);
}

// ---------------------------------------------------------------------------
// K3: MFMA main — DIRECT per-lane fragment loads from global, NO in-loop LDS,
// NO in-loop barriers. Rationale: each A element feeds exactly one lane's
// fragment (row m = lane&15, k window quad*8..+8), so LDS staging bought
// nothing and cost a 2-barrier/chunk lockstep pipeline (suspected cause of
// the ~10%-of-HBM plateau). A wave's two dwordx4 loads per iteration jointly
// cover 16 rows x 128 B contiguous, 128 B-aligned -> full L2-line use.
// B (packed bits) is L2-resident, broadcast across the 16 m-lanes of a quad.
// Each wave independently streams a contiguous 1024-k quarter (32 iters).
// Grid = B*QT16*KG = 832 wgs of 256; LDS only for the epilogue C-reduce.
__global__ __launch_bounds__(256) void k_mfma(const float* __restrict__ pm,
                                              const uint32_t* __restrict__ packed,
                                              float* __restrict__ inter,   // [B][32][QP]
                                              float* __restrict__ psum) {  // [B][QP]
    int blk = blockIdx.x;
    int b   = blk / (QT16 * KG);
    int rem = blk % (QT16 * KG);
    int qt  = rem / KG;
    int kg  = rem % KG;
    int tid = threadIdx.x, lane = tid & 63, wave = tid >> 6;
    int m = lane & 15, quad = lane >> 4;   // m: A-row / C-col(n) / B-bit

    int qg_m = qt * 16 + m;
    int qrow = qg_m < QQ ? qg_m : QQ - 1;  // clamped rows masked at output

    const float*    ap = pm + ((size_t)b * QQ + qrow) * DD
                            + (size_t)kg * KSPAN + wave * KQ + quad * 8;
    const uint32_t* bp = packed + (size_t)b * DD
                                + (size_t)kg * KSPAN + wave * KQ + quad * 8;

    f32x4 cH0 = {0.f,0.f,0.f,0.f}, cL0 = {0.f,0.f,0.f,0.f};
    f32x4 cH1 = {0.f,0.f,0.f,0.f}, cL1 = {0.f,0.f,0.f,0.f};
    float ps = 0.f;

#pragma unroll 2
    for (int it = 0; it < NIT; ++it) {
        float4 a0 = *(const float4*)(ap + it * 32);
        float4 a1 = *(const float4*)(ap + it * 32 + 4);
        uint4  w0 = *(const uint4*)(bp + it * 32);
        uint4  w1 = *(const uint4*)(bp + it * 32 + 4);

        // A: sigmoid + exact 3-term split (hi/mid/lo bit-truncation)
        float xs[8] = {a0.x, a0.y, a0.z, a0.w, a1.x, a1.y, a1.z, a1.w};
        uint32_t hu[8], mu[8], lu[8];
#pragma unroll
        for (int i = 0; i < 8; ++i) {
            float x  = xs[i];
            float sg = __builtin_amdgcn_rcpf(1.0f + __expf(-x));
            ps += sg;
            uint32_t u0 = __float_as_uint(sg);
            float hi = __uint_as_float(u0 & 0xFFFF0000u);
            float r1 = sg - hi;                      // exact
            uint32_t u1 = __float_as_uint(r1);
            float mi = __uint_as_float(u1 & 0xFFFF0000u);
            float r2 = r1 - mi;                      // exact, <=8 sig bits
            hu[i] = u0; mu[i] = u1; lu[i] = __float_as_uint(r2);
        }
        union { uint4 u; bf16x8 v; } ah, am, al;
        ah.u = make_uint4((hu[0] >> 16) | (hu[1] & 0xFFFF0000u),
                          (hu[2] >> 16) | (hu[3] & 0xFFFF0000u),
                          (hu[4] >> 16) | (hu[5] & 0xFFFF0000u),
                          (hu[6] >> 16) | (hu[7] & 0xFFFF0000u));
        am.u = make_uint4((mu[0] >> 16) | (mu[1] & 0xFFFF0000u),
                          (mu[2] >> 16) | (mu[3] & 0xFFFF0000u),
                          (mu[4] >> 16) | (mu[5] & 0xFFFF0000u),
                          (mu[6] >> 16) | (mu[7] & 0xFFFF0000u));
        al.u = make_uint4((lu[0] >> 16) | (lu[1] & 0xFFFF0000u),
                          (lu[2] >> 16) | (lu[3] & 0xFFFF0000u),
                          (lu[4] >> 16) | (lu[5] & 0xFFFF0000u),
                          (lu[6] >> 16) | (lu[7] & 0xFFFF0000u));

        // B: bits m (n=0..15) and 16+m (n=16..31) of 8 words -> bf16 0/1
        uint32_t wj[8] = {w0.x, w0.y, w0.z, w0.w, w1.x, w1.y, w1.z, w1.w};
        union { ushort u[8]; bf16x8 v; } b0, b1;
#pragma unroll
        for (int j = 0; j < 8; ++j) {
            b0.u[j] = (ushort)((((int)(wj[j] << (31 - m))) >> 31) & 0x3F80);
            b1.u[j] = (ushort)((((int)(wj[j] << (15 - m))) >> 31) & 0x3F80);
        }

        cH0 = __builtin_amdgcn_mfma_f32_16x16x32_bf16(ah.v, b0.v, cH0, 0, 0, 0);
        cL0 = __builtin_amdgcn_mfma_f32_16x16x32_bf16(am.v, b0.v, cL0, 0, 0, 0);
        cL0 = __builtin_amdgcn_mfma_f32_16x16x32_bf16(al.v, b0.v, cL0, 0, 0, 0);
        cH1 = __builtin_amdgcn_mfma_f32_16x16x32_bf16(ah.v, b1.v, cH1, 0, 0, 0);
        cL1 = __builtin_amdgcn_mfma_f32_16x16x32_bf16(am.v, b1.v, cL1, 0, 0, 0);
        cL1 = __builtin_amdgcn_mfma_f32_16x16x32_bf16(al.v, b1.v, cL1, 0, 0, 0);
    }

    // psum: lanes m, m+16, m+32, m+48 share q-row m (disjoint k)
    ps += __shfl_xor(ps, 16);
    ps += __shfl_xor(ps, 32);
    if (lane < 16) {
        int qg = qt * 16 + m;
        if (qg < QQ) atomicAdd(&psum[b * QP + qg], ps);
    }

    // cross-wave C reduce in LDS (stride 9: gcd(9,32)=1), one atomic set/wg.
    __shared__ float cred[3 * 64 * 9];   // 6.9 KB
    float c8[8];
#pragma unroll
    for (int r = 0; r < 4; ++r) {
        c8[r]     = cH0[r] + cL0[r];
        c8[4 + r] = cH1[r] + cL1[r];
    }
    __syncthreads();
    if (wave > 0) {
        float* dst = cred + ((wave - 1) * 64 + lane) * 9;
#pragma unroll
        for (int r = 0; r < 8; ++r) dst[r] = c8[r];
    }
    __syncthreads();
    if (wave == 0) {
#pragma unroll
        for (int wv = 0; wv < 3; ++wv) {
            const float* sp = cred + (wv * 64 + lane) * 9;
#pragma unroll
            for (int r = 0; r < 8; ++r) c8[r] += sp[r];
        }
        // C layout (16x16, m89): col(n) = lane&15, row(q) = quad*4 + r
#pragma unroll
        for (int r = 0; r < 4; ++r) {
            int qg = qt * 16 + quad * 4 + r;
            if (qg < QQ) {
                atomicAdd(&inter[(b * NGT + m) * QP + qg],      c8[r]);
                atomicAdd(&inter[(b * NGT + 16 + m) * QP + qg], c8[4 + r]);
            }
        }
    }
}

// ---------------------------------------------------------------------------
// K4: parallel top-4 per (b,n); combined = iou*cls computed on the fly.
__global__ __launch_bounds__(64) void k_topk(const float* __restrict__ inter,
                                             const float* __restrict__ psum,
                                             const float* __restrict__ tsum,
                                             const float* __restrict__ logits,
                                             int* __restrict__ idx4) {
    int bn = blockIdx.x;            // b*32 + n
    int b  = bn >> 5;
    int lane = threadIdx.x;
    float tsn = tsum[bn];
    float v[4];
#pragma unroll
    for (int s = 0; s < 4; ++s) {
        int q = lane + 64 * s;
        if (q < QQ) {
            float iv = inter[(size_t)bn * QP + q];
            float un = psum[b * QP + q] + tsn - iv;
            float l0 = logits[(b * QQ + q) * 2];
            float l1 = logits[(b * QQ + q) * 2 + 1];
            float cl = 1.0f / (1.0f + expf(l0 - l1));
            v[s] = iv / (un + EPSF) * cl;
        } else {
            v[s] = -INFINITY;
        }
    }
    for (int k = 0; k < TOPK; ++k) {
        float bv = -INFINITY;
        int   bi = 0x7fffffff;
#pragma unroll
        for (int s = 0; s < 4; ++s)
            if (v[s] > bv) { bv = v[s]; bi = lane + 64 * s; }
#pragma unroll
        for (int off = 32; off; off >>= 1) {
            float ov = __shfl_xor(bv, off);
            int   oi = __shfl_xor(bi, off);
            if (ov > bv || (ov == bv && oi < bi)) { bv = ov; bi = oi; }
        }
        if (lane == (bi & 63)) v[bi >> 6] = -INFINITY;
        if (lane == 0) idx4[bn * TOPK + k] = bi;
    }
}

// ---------------------------------------------------------------------------
// K5: sequential dedup over GTs (indices precomputed). One wave per b.
__global__ __launch_bounds__(64) void k_final(const int* __restrict__ idx4,
                                              int* __restrict__ out) {
    int b = blockIdx.x;
    int lane = threadIdx.x;
    int* src = out;
    int* tgt = out + BB * NGT * TOPK;
    int* val = out + 2 * BB * NGT * TOPK;
    int asg = 0;   // 4 assigned bits: q = lane + 64*slot
    for (int n = 0; n < NGT; ++n) {
        int4 id = *(const int4*)&idx4[(b * NGT + n) * TOPK];
        int ids[4] = {id.x, id.y, id.z, id.w};
        int newasg = asg;
#pragma unroll
        for (int k = 0; k < TOPK; ++k) {
            int idx = ids[k];                      // uniform across lanes
            int owner = idx & 63, slot = idx >> 6;
            int oasg = __shfl(asg, owner);         // pre-n state (idx distinct in n)
            int taken = (oasg >> slot) & 1;
            if (lane == owner) newasg |= (1 << slot);
            if (lane == 0) {
                int o = (b * NGT + n) * TOPK + k;
                src[o] = taken ? -1 : idx;
                tgt[o] = taken ? -1 : n;
                val[o] = taken ? 0 : 1;
            }
        }
        asg = newasg;
    }
}

// ---------------------------------------------------------------------------
extern "C" void kernel_launch(void* const* d_in, const int* in_sizes, int n_in,
                              void* d_out, int out_size, void* d_ws, size_t ws_size,
                              hipStream_t stream) {
    const float* pred_masks  = (const float*)d_in[0];  // [4,200,256,256]
    const float* pred_logits = (const float*)d_in[1];  // [4,200,2]
    const float* gt_masks    = (const float*)d_in[2];  // [4,32,256,256]

    uint8_t* ws = (uint8_t*)d_ws;
    uint32_t* packed = (uint32_t*)ws;                   // 1 MB
    float* tsum  = (float*)(ws + (size_t)BB * DD * 4);  // 128
    float* inter = tsum + BB * NGT;                     // 26624 (zeroed by k_pack)
    float* psum  = inter + BB * NGT * QP;               // 832   (zeroed, contiguous)
    int*   idx4  = (int*)(psum + BB * QP);              // 512

    k_pack <<<BB * (DD / 1024), 256, 0, stream>>>(gt_masks, packed, inter);
    k_tsum <<<BB * NGT,         256, 0, stream>>>(packed, tsum);
    k_mfma <<<BB * QT16 * KG,   256, 0, stream>>>(pred_masks, packed, inter, psum);
    k_topk <<<BB * NGT,          64, 0, stream>>>(inter, psum, tsum, pred_logits, idx4);
    k_final<<<BB,                64, 0, stream>>>(idx4, (int*)d_out);
}